// Round 3
// baseline (163.316 us; speedup 1.0000x reference)
//
#include <hip/hip_runtime.h>

#define HID   384
#define K_PE  768     // 3*16*16
#define IMGST 150528  // 3*224*224 floats per image
#define POS   196

typedef unsigned short ushort_t;
using f32x4  = __attribute__((ext_vector_type(4))) float;
using short8 = __attribute__((ext_vector_type(8))) short;

typedef unsigned __attribute__((address_space(1))) u32_g;
typedef unsigned __attribute__((address_space(3))) u32_s;

__device__ __forceinline__ void glds16(const void* g, void* l) {
    __builtin_amdgcn_global_load_lds((const u32_g*)g, (u32_s*)l, 16, 0, 0);
}

// ---- bf16 helpers (RNE) ----------------------------------------------------
__device__ __forceinline__ unsigned bfpack(float lo, float hi) {
    union { float f; unsigned u; } a, b; a.f = lo; b.f = hi;
    unsigned ra = (a.u + 0x7fffu + ((a.u >> 16) & 1u)) >> 16;
    unsigned rb = (b.u + 0x7fffu + ((b.u >> 16) & 1u)) & 0xffff0000u;
    return ra | rb;
}

// ---------------- pack: im2col transpose (contiguous HBM both sides) --------
// blocks 0..1791: (pi, img, tensor). Read band [3][16][224] f32 contiguously,
// bf16 into LDS, write im2col[p][kbi][img][oct*16B] (absorbed by L2/L3).
// 21.8 KB LDS -> 7 blocks/CU.
// blocks 1792..1935: W swizzle into B-frag order + zero scal/pcnt/Lp/Qp.
__global__ __launch_bounds__(256) void pack(
    const float* __restrict__ x, const float* __restrict__ y,
    const float* __restrict__ W, ushort_t* __restrict__ Wfrag,
    ushort_t* __restrict__ imx, ushort_t* __restrict__ imy,
    float* __restrict__ scal, int* __restrict__ pcnt,
    float* __restrict__ Lp, float* __restrict__ Qp) {
    const int b   = blockIdx.x;
    const int tid = threadIdx.x;

    if (b >= 1792) {           // ---- W-prep + workspace zeroing ----
        const int t = (b - 1792) * 256 + tid;  // 0..36863
        if (t < 16)  scal[t] = 0.f;            // T, S, pad, done-counter
        if (t < POS) pcnt[t] = 0;
        for (int i = t; i < POS * HID; i += 36864) { Lp[i] = 0.f; Qp[i] = 0.f; }
        const int n  = t / 96;                 // 0..383
        const int ko = t - n * 96;             // k-octet
        const float4 a  = *(const float4*)(W + (size_t)n * K_PE + ko * 8);
        const float4 bb = *(const float4*)(W + (size_t)n * K_PE + ko * 8 + 4);
        uint4 pq;
        pq.x = bfpack(a.x, a.y);   pq.y = bfpack(a.z, a.w);
        pq.z = bfpack(bb.x, bb.y); pq.w = bfpack(bb.z, bb.w);
        const int nt    = n >> 4;
        const int kc    = ko >> 2;
        const int lanew = (ko & 3) * 16 + (n & 15);
        ((uint4*)Wfrag)[(nt * 24 + kc) * 64 + lanew] = pq;
        return;
    }

    const int pi  = b >> 7;          // 0..13
    const int img = (b >> 1) & 63;   // 0..63
    const int tn  = b & 1;           // 0:x  1:y
    // padded LDS: row stride 232 ushorts breaks the 896-B-period bank pattern
    __shared__ __align__(16) ushort_t L[48 * 232];

    const float* bp = (tn ? y : x) + (size_t)img * IMGST + pi * 3584;

    // phase 1: contiguous read, bf16 convert, LDS (source layout)
    for (int i = tid; i < 2688; i += 256) {          // 48 rows x 56 float4
        const int row = i / 56;                      // c*16 + r
        const int c4  = i - row * 56;
        const int c   = row >> 4, r = row & 15;
        const size_t so = (size_t)c * 50176 + r * 224 + c4 * 4;
        const float4 f = *(const float4*)(bp + so);
        uint2 px;
        px.x = bfpack(f.x, f.y); px.y = bfpack(f.z, f.w);
        *(uint2*)&L[row * 232 + c4 * 4] = px;
    }
    __syncthreads();

    // phase 2: k-major gather from LDS, 16-B aligned writes to im2col
    ushort_t* __restrict__ im = tn ? imy : imx;
    for (int u = tid; u < 1344; u += 256) {          // 14 pj x 96 octs
        const int pj  = u / 96;
        const int oc  = u - pj * 96;
        const int kbi = oc >> 3, o = oc & 7;
        const int k0  = oc * 8;
        const int c   = k0 >> 8, kh = (k0 >> 4) & 15, kw0 = k0 & 15;
        const int loff = (c * 16 + kh) * 232 + pj * 16 + kw0;   // 16-B aligned
        const uint4 v = *(const uint4*)&L[loff];
        const size_t d = ((size_t)((pi * 14 + pj) * 12 + kbi) * 64 + img) * 64 + o * 8;
        *(uint4*)&im[d] = v;
    }
}

// ---------------- fused GEMM + softmax + full reduction ----------------------
// grid 784 = 196 positions x 4 image-quarters (M=16). block 256 = 4 n-waves.
// 3.06 blocks/CU average -> whole grid co-resident; barrier drains in one
// block overlap MFMA phases of other blocks. A staged via global_load_lds
// (one 16-B op per thread per K-step, source pre-swizzled, linear LDS dest).
// Per wave per K-step: 24 MFMA vs 12 x 16-B bfr loads + 4 ds_read_b128.
// Epilogue: fused softmax; T -> atomicAdd; col sums -> atomicAdd Lp/Qp;
// 4th block per position computes S_p; last block overall writes out.
__global__ __launch_bounds__(256, 4) void pe3(
    const ushort_t* __restrict__ imx, const ushort_t* __restrict__ imy,
    const ushort_t* __restrict__ Wfrag, const float* __restrict__ bias,
    float* __restrict__ scal, int* __restrict__ pcnt,
    float* __restrict__ Lp, float* __restrict__ Qp, float* __restrict__ out) {
    const int blk = blockIdx.x;        // 0..783
    const int p   = blk >> 2;          // position
    const int sub = blk & 3;           // image quarter

    __shared__ __align__(16) ushort_t As[2][2048];  // [buf][x:0..1023 | y:1024..2047]
    __shared__ float Smx[4][16], Ssx[4][16], Smy[4][16], Ssy[4][16];
    __shared__ float sT[4];
    __shared__ int lastp;

    const int tid  = threadIdx.x;
    const int wave = tid >> 6;         // n-wave: cols wave*96..+96
    const int lane = tid & 63;
    const int lm   = lane & 15;
    const int lq   = lane >> 4;

    // ---- stage mapping: thread -> (tensor, row, slot); slot holds oct^(row&7)
    const int t_   = tid >> 7;                 // 0:x 1:y
    const int srow = (tid & 127) >> 3;         // 0..15
    const int s_   = lane & 7;                 // physical slot
    const int o_   = s_ ^ (srow & 7);          // logical oct at this slot
    const char* gsrc = (const char*)(t_ ? imy : imx) +
        (size_t)p * 98304 + (size_t)(sub * 16 + srow) * 128 + o_ * 16;
    const int wbase = wave * 512;              // wave-uniform LDS dest (ushorts)

    // ---- frag read offsets: As[row*64 + (oct^(row&7))*8], oct = ks*4+lq
    int ard[2];
#pragma unroll
    for (int ks = 0; ks < 2; ++ks)
        ard[ks] = lm * 64 + (((ks * 4 + lq) ^ (lm & 7)) * 8);

    const ushort_t* bbase = Wfrag + (size_t)lane * 8;

    f32x4 accx[6] = {};
    f32x4 accy[6] = {};

#define STAGE(KB, BUF) glds16(gsrc + (size_t)(KB) * 8192, &As[BUF][wbase]);

    STAGE(0, 0)
    __syncthreads();

    for (int kbi = 0; kbi < 12; ++kbi) {
        const int cur = kbi & 1;
#pragma unroll
        for (int ks = 0; ks < 2; ++ks) {
            short8 bfr[6];
#pragma unroll
            for (int ni = 0; ni < 6; ++ni)
                bfr[ni] = *(const short8*)(bbase +
                          (size_t)(((wave * 6 + ni) * 24 + kbi * 2 + ks) * 64) * 8);
            if (ks == 0 && kbi < 11) STAGE(kbi + 1, cur ^ 1)
            const short8 afx = *(const short8*)&As[cur][ard[ks]];
            const short8 afy = *(const short8*)&As[cur][1024 + ard[ks]];
#pragma unroll
            for (int ni = 0; ni < 6; ++ni) {
                accx[ni] = __builtin_amdgcn_mfma_f32_16x16x32_bf16(
                    afx, bfr[ni], accx[ni], 0, 0, 0);
                accy[ni] = __builtin_amdgcn_mfma_f32_16x16x32_bf16(
                    afy, bfr[ni], accy[ni], 0, 0, 0);
            }
        }
        __syncthreads();
    }
#undef STAGE

    // ---- epilogue: D col = wave*96 + ni*16 + lm; row = lq*4 + r (16 rows)
#pragma unroll
    for (int ni = 0; ni < 6; ++ni) {
        const float bv = bias[wave * 96 + ni * 16 + lm];
#pragma unroll
        for (int r = 0; r < 4; ++r) {
            accx[ni][r] += bv;
            accy[ni][r] += bv;
        }
    }

    // row max over this wave's 96 cols, butterfly within the 16-lane lm group
    float mx[4], my_[4];
#pragma unroll
    for (int r = 0; r < 4; ++r) {
        float a = accx[0][r], bb = accy[0][r];
#pragma unroll
        for (int ni = 1; ni < 6; ++ni) {
            a  = fmaxf(a,  accx[ni][r]);
            bb = fmaxf(bb, accy[ni][r]);
        }
        mx[r] = a; my_[r] = bb;
    }
#pragma unroll
    for (int off = 1; off < 16; off <<= 1)
#pragma unroll
        for (int r = 0; r < 4; ++r) {
            mx[r]  = fmaxf(mx[r],  __shfl_xor(mx[r],  off));
            my_[r] = fmaxf(my_[r], __shfl_xor(my_[r], off));
        }
    if (lm == 0)
#pragma unroll
        for (int r = 0; r < 4; ++r) {
            Smx[wave][lq * 4 + r] = mx[r];
            Smy[wave][lq * 4 + r] = my_[r];
        }
    __syncthreads();
#pragma unroll
    for (int r = 0; r < 4; ++r) {
        const int row = lq * 4 + r;
        mx[r]  = fmaxf(fmaxf(Smx[0][row], Smx[1][row]),
                       fmaxf(Smx[2][row], Smx[3][row]));
        my_[r] = fmaxf(fmaxf(Smy[0][row], Smy[1][row]),
                       fmaxf(Smy[2][row], Smy[3][row]));
    }

    // row sum of exp against the full-row max
    float sx[4], sy[4];
#pragma unroll
    for (int r = 0; r < 4; ++r) {
        float a = 0.f, bb = 0.f;
#pragma unroll
        for (int ni = 0; ni < 6; ++ni) {
            a  += __expf(accx[ni][r] - mx[r]);
            bb += __expf(accy[ni][r] - my_[r]);
        }
        sx[r] = a; sy[r] = bb;
    }
#pragma unroll
    for (int off = 1; off < 16; off <<= 1)
#pragma unroll
        for (int r = 0; r < 4; ++r) {
            sx[r] += __shfl_xor(sx[r], off);
            sy[r] += __shfl_xor(sy[r], off);
        }
    if (lm == 0)
#pragma unroll
        for (int r = 0; r < 4; ++r) {
            Ssx[wave][lq * 4 + r] = sx[r];
            Ssy[wave][lq * 4 + r] = sy[r];
        }
    __syncthreads();
    float shx[4], invy[4];
#pragma unroll
    for (int r = 0; r < 4; ++r) {
        const int row = lq * 4 + r;
        const float ssx = Ssx[0][row] + Ssx[1][row] + Ssx[2][row] + Ssx[3][row];
        const float ssy = Ssy[0][row] + Ssy[1][row] + Ssy[2][row] + Ssy[3][row];
        shx[r]  = mx[r] + __logf(ssx);   // logp shift
        invy[r] = 1.f / ssy;             // q scale
    }

    // T partial + per-column sums over this block's 16 rows
    float T = 0.f;
    float cL[6], cQ[6];
#pragma unroll
    for (int ni = 0; ni < 6; ++ni) { cL[ni] = 0.f; cQ[ni] = 0.f; }
#pragma unroll
    for (int r = 0; r < 4; ++r) {
        const float sh  = shx[r];
        const float m   = my_[r];
        const float inv = invy[r];
#pragma unroll
        for (int ni = 0; ni < 6; ++ni) {
            const float lp = accx[ni][r] - sh;
            const float qv = __expf(accy[ni][r] - m) * inv;
            T += lp * qv;
            cL[ni] += lp;
            cQ[ni] += qv;
        }
    }
    // reduce col sums over lq (lanes lm, lm+16, lm+32, lm+48)
#pragma unroll
    for (int ni = 0; ni < 6; ++ni) {
        cL[ni] += __shfl_xor(cL[ni], 16); cL[ni] += __shfl_xor(cL[ni], 32);
        cQ[ni] += __shfl_xor(cQ[ni], 16); cQ[ni] += __shfl_xor(cQ[ni], 32);
    }
    if (lq == 0)
#pragma unroll
        for (int ni = 0; ni < 6; ++ni) {
            atomicAdd(&Lp[p * HID + wave * 96 + ni * 16 + lm], cL[ni]);
            atomicAdd(&Qp[p * HID + wave * 96 + ni * 16 + lm], cQ[ni]);
        }
    // wave-reduce T, block sum -> global atomic; count blocks of this position
#pragma unroll
    for (int off = 32; off > 0; off >>= 1) T += __shfl_xor(T, off);
    if (lane == 0) sT[wave] = T;
    __syncthreads();
    if (tid == 0) {
        atomicAdd(&scal[0], sT[0] + sT[1] + sT[2] + sT[3]);
        __threadfence();
        const int old = atomicAdd(&pcnt[p], 1);
        lastp = (old == 3);
    }
    __syncthreads();

    if (lastp) {   // 4th block of this position: S_p = sum_c L*Q
        float s = 0.f;
        for (int c = tid; c < HID; c += 256) {
            const float Lv = atomicAdd(&Lp[p * HID + c], 0.f);
            const float Qv = atomicAdd(&Qp[p * HID + c], 0.f);
            s += Lv * Qv;
        }
#pragma unroll
        for (int off = 32; off > 0; off >>= 1) s += __shfl_xor(s, off);
        if (lane == 0) sT[wave] = s;
        __syncthreads();
        if (tid == 0) atomicAdd(&scal[1], sT[0] + sT[1] + sT[2] + sT[3]);
    }

    if (tid == 0) {
        __threadfence();
        const int g = atomicAdd((int*)&scal[3], 1);
        if (g == (int)gridDim.x - 1) {
            const float Tt = atomicAdd(&scal[0], 0.f);   // coherent read-back
            const float St = atomicAdd(&scal[1], 0.f);
            out[0] = 63.f * Tt / (St - Tt);
        }
    }
}

extern "C" void kernel_launch(void* const* d_in, const int* in_sizes, int n_in,
                              void* d_out, int out_size, void* d_ws, size_t ws_size,
                              hipStream_t stream) {
    const float* x = (const float*)d_in[0];   // (64,3,224,224)
    const float* y = (const float*)d_in[1];   // (64,3,224,224)
    const float* W = (const float*)d_in[2];   // (384,768)
    const float* b = (const float*)d_in[3];   // (384,)
    float* out = (float*)d_out;

    char* ws = (char*)d_ws;
    float*    scal  = (float*)ws;                      // 1 KB
    int*      pcnt  = (int*)(ws + 1024);               // 196 ints
    ushort_t* Wfrag = (ushort_t*)(ws + 2048);          // 589,824 B
    float*    Lp    = (float*)(ws + 591872);           // 301,056 B
    float*    Qp    = (float*)(ws + 892928);           // 301,056 B
    ushort_t* imx   = (ushort_t*)(ws + 1196032);       // 19,267,584 B
    ushort_t* imy   = (ushort_t*)(ws + 20463616);      // 19,267,584 B

    pack<<<1936, 256, 0, stream>>>(x, y, W, Wfrag, imx, imy, scal, pcnt, Lp, Qp);
    pe3<<<784, 256, 0, stream>>>(imx, imy, Wfrag, b, scal, pcnt, Lp, Qp, out);
}

// Round 4
// 150.987 us; speedup vs baseline: 1.0817x; 1.0817x over previous
//
#include <hip/hip_runtime.h>

#define HID   384
#define K_PE  768     // 3*16*16
#define IMGST 150528  // 3*224*224 floats per image
#define POS   196

typedef unsigned short ushort_t;
using f32x4  = __attribute__((ext_vector_type(4))) float;
using short8 = __attribute__((ext_vector_type(8))) short;

// ---- bf16 helpers (RNE) ----------------------------------------------------
__device__ __forceinline__ unsigned bfpack(float lo, float hi) {
    union { float f; unsigned u; } a, b; a.f = lo; b.f = hi;
    unsigned ra = (a.u + 0x7fffu + ((a.u >> 16) & 1u)) >> 16;
    unsigned rb = (b.u + 0x7fffu + ((b.u >> 16) & 1u)) & 0xffff0000u;
    return ra | rb;
}

// ---------------- prep: zero scalars + swizzle W into B-frag order ----------
// Wfrag: [nt(24)][kc(24)][lane(64)][8] bf16; B-frag n = nt*16 + (lane&15),
// k = kc*32 + (lane>>4)*8 + j. grid 144 x 256 = 384 rows x 96 k-octets.
__global__ __launch_bounds__(256) void prep(const float* __restrict__ W,
                                            ushort_t* __restrict__ Wfrag,
                                            float* __restrict__ scal) {
    const int t = blockIdx.x * 256 + threadIdx.x;
    if (t < 4) scal[t] = 0.f;                  // T, S, pad, done-counter
    const int n  = t / 96;                     // 0..383
    const int ko = t - n * 96;                 // k-octet
    const float4 a  = *(const float4*)(W + (size_t)n * K_PE + ko * 8);
    const float4 bb = *(const float4*)(W + (size_t)n * K_PE + ko * 8 + 4);
    uint4 pq;
    pq.x = bfpack(a.x, a.y);   pq.y = bfpack(a.z, a.w);
    pq.z = bfpack(bb.x, bb.y); pq.w = bfpack(bb.z, bb.w);
    const int nt    = n >> 4;
    const int kc    = ko >> 2;
    const int lanew = (ko & 3) * 16 + (n & 15);
    ((uint4*)Wfrag)[(nt * 24 + kc) * 64 + lanew] = pq;
}

// ---------------- fused im2col + GEMM + softmax ------------------------------
// grid 448 = 14 pi x 32 img-pairs. block 256 = 4 n-waves (96 cols each).
// M = 32 rows/tensor = 2 imgs x 14 pj (+4 pad dup of row 27). K-loop: 24
// steps of (c, kh-pair); per step the block reads 8 fully-contiguous 896-B
// HBM rows (2img x 2tensor x 2kh), packs bf16 into k-major LDS. x/y read
// EXACTLY ONCE, coalesced. B-frags register-prefetched one step ahead (no
// per-step L2 stall); A staged T14 (issue-early / write-late); single
// barrier per step; #pragma unroll 2 makes buffer parity compile-time.
// Epilogue: fused softmax; T -> atomicAdd; logp/q stored per-element to
// Lg/Qg[pi][img][pj][c] (L3-resident) for the position-wise S reduction.
__global__ __launch_bounds__(256, 2) void pef(
    const float* __restrict__ x, const float* __restrict__ y,
    const ushort_t* __restrict__ Wfrag, const float* __restrict__ bias,
    float* __restrict__ scal, float* __restrict__ Lg, float* __restrict__ Qg) {
    const int blk = blockIdx.x;        // 0..447
    const int pi  = blk >> 5;          // 0..13
    const int ig  = blk & 31;          // img pair (imgs ig*2, ig*2+1)

    // A LDS: [buf][lq(4)=khsel*2+q][t(2)][img(2)][pj(14)][8 ush] = 2 x 3.5 KB
    __shared__ __align__(16) ushort_t As[2][1792];
    __shared__ float Smx[4][32], Ssx[4][32], Smy[4][32], Ssy[4][32];
    __shared__ float sT[4];

    const int tid  = threadIdx.x;
    const int wave = tid >> 6;         // n-wave: cols wave*96..+96
    const int lane = tid & 63;
    const int lm   = lane & 15;
    const int lq   = lane >> 4;

    // ---- staging ids: rr = (t, img, khsel) row; sj -> (pj, q)
    const int rr   = tid >> 5;         // 0..7
    const int sj   = tid & 31;         // 0..31, active < 28
    const int st   = rr >> 2;
    const int simg = (rr >> 1) & 1;
    const int skh  = rr & 1;
    const int sq   = sj & 1;
    const int spj  = sj >> 1;
    const bool sact = sj < 28;
    const float* srow = (st ? y : x) +
        (size_t)(ig * 2 + simg) * IMGST + pi * 3584 + sj * 8;
    const int aoff = (((skh * 2 + sq) * 2 + st) * 2 + simg) * 112 + spj * 8;

    // ---- A-frag read offsets: m = mi*16+lm -> (img,pj); k-octet = lq
    int ard[2][2];
#pragma unroll
    for (int t = 0; t < 2; ++t)
#pragma unroll
        for (int mi = 0; mi < 2; ++mi) {
            int m = mi * 16 + lm; if (m > 27) m = 27;   // pad rows dup row 27
            const int img = (m >= 14) ? 1 : 0;
            const int pj  = m - img * 14;
            ard[t][mi] = ((lq * 2 + t) * 2 + img) * 112 + pj * 8;
        }

    f32x4 accx[2][6] = {};
    f32x4 accy[2][6] = {};

    // ---- prologue: stage step 0, preload B-frags for step 0
    if (sact) {
        const float4 f0 = *(const float4*)(srow + skh * 224);
        const float4 f1 = *(const float4*)(srow + skh * 224 + 4);
        uint4 px;
        px.x = bfpack(f0.x, f0.y); px.y = bfpack(f0.z, f0.w);
        px.z = bfpack(f1.x, f1.y); px.w = bfpack(f1.z, f1.w);
        *(uint4*)&As[0][aoff] = px;
    }
    short8 bfr[6];
#pragma unroll
    for (int ni = 0; ni < 6; ++ni)
        bfr[ni] = *(const short8*)(Wfrag +
                  (size_t)(((wave * 6 + ni) * 24) * 64 + lane) * 8);
    __syncthreads();

#pragma unroll 2
    for (int kk = 0; kk < 24; ++kk) {
        const int cur = kk & 1;
        const int kn  = (kk < 23) ? kk + 1 : 0;   // clamp: stay in-bounds
        // T14: issue next-step A loads now (consumed after MFMAs)
        const int off = (kn >> 3) * 50176 + ((kn & 7) * 2 + skh) * 224;
        float4 f0{}, f1{};
        if (sact) {
            f0 = *(const float4*)(srow + off);
            f1 = *(const float4*)(srow + off + 4);
        }
        // B prefetch for next step (removes per-step L2 stall)
        short8 bfrn[6];
#pragma unroll
        for (int ni = 0; ni < 6; ++ni)
            bfrn[ni] = *(const short8*)(Wfrag +
                       (size_t)(((wave * 6 + ni) * 24 + kn) * 64 + lane) * 8);
        // A frags from LDS
        short8 af[2][2];
#pragma unroll
        for (int t = 0; t < 2; ++t)
#pragma unroll
            for (int mi = 0; mi < 2; ++mi)
                af[t][mi] = *(const short8*)&As[cur][ard[t][mi]];
        // 24 MFMAs
#pragma unroll
        for (int mi = 0; mi < 2; ++mi)
#pragma unroll
            for (int ni = 0; ni < 6; ++ni) {
                accx[mi][ni] = __builtin_amdgcn_mfma_f32_16x16x32_bf16(
                    af[0][mi], bfr[ni], accx[mi][ni], 0, 0, 0);
                accy[mi][ni] = __builtin_amdgcn_mfma_f32_16x16x32_bf16(
                    af[1][mi], bfr[ni], accy[mi][ni], 0, 0, 0);
            }
        // write-late: vmcnt wait + pack + LDS store after the MFMAs
        if (sact) {
            uint4 px;
            px.x = bfpack(f0.x, f0.y); px.y = bfpack(f0.z, f0.w);
            px.z = bfpack(f1.x, f1.y); px.w = bfpack(f1.z, f1.w);
            *(uint4*)&As[cur ^ 1][aoff] = px;
        }
#pragma unroll
        for (int ni = 0; ni < 6; ++ni) bfr[ni] = bfrn[ni];
        __syncthreads();
    }

    // ---- epilogue: D col = wave*96 + ni*16 + lm; row = mi*16 + lq*4 + r
#pragma unroll
    for (int ni = 0; ni < 6; ++ni) {
        const float bv = bias[wave * 96 + ni * 16 + lm];
#pragma unroll
        for (int mi = 0; mi < 2; ++mi)
#pragma unroll
            for (int r = 0; r < 4; ++r) {
                accx[mi][ni][r] += bv;
                accy[mi][ni][r] += bv;
            }
    }

    float mx[2][4], my_[2][4];
#pragma unroll
    for (int mi = 0; mi < 2; ++mi)
#pragma unroll
        for (int r = 0; r < 4; ++r) {
            float a = accx[mi][0][r], bb = accy[mi][0][r];
#pragma unroll
            for (int ni = 1; ni < 6; ++ni) {
                a  = fmaxf(a,  accx[mi][ni][r]);
                bb = fmaxf(bb, accy[mi][ni][r]);
            }
            mx[mi][r] = a; my_[mi][r] = bb;
        }
#pragma unroll
    for (int off = 1; off < 16; off <<= 1)
#pragma unroll
        for (int mi = 0; mi < 2; ++mi)
#pragma unroll
            for (int r = 0; r < 4; ++r) {
                mx[mi][r]  = fmaxf(mx[mi][r],  __shfl_xor(mx[mi][r],  off));
                my_[mi][r] = fmaxf(my_[mi][r], __shfl_xor(my_[mi][r], off));
            }
    if (lm == 0)
#pragma unroll
        for (int mi = 0; mi < 2; ++mi)
#pragma unroll
            for (int r = 0; r < 4; ++r) {
                Smx[wave][mi * 16 + lq * 4 + r] = mx[mi][r];
                Smy[wave][mi * 16 + lq * 4 + r] = my_[mi][r];
            }
    __syncthreads();
#pragma unroll
    for (int mi = 0; mi < 2; ++mi)
#pragma unroll
        for (int r = 0; r < 4; ++r) {
            const int row = mi * 16 + lq * 4 + r;
            mx[mi][r]  = fmaxf(fmaxf(Smx[0][row], Smx[1][row]),
                               fmaxf(Smx[2][row], Smx[3][row]));
            my_[mi][r] = fmaxf(fmaxf(Smy[0][row], Smy[1][row]),
                               fmaxf(Smy[2][row], Smy[3][row]));
        }

    float sx[2][4], sy[2][4];
#pragma unroll
    for (int mi = 0; mi < 2; ++mi)
#pragma unroll
        for (int r = 0; r < 4; ++r) {
            float a = 0.f, bb = 0.f;
#pragma unroll
            for (int ni = 0; ni < 6; ++ni) {
                a  += __expf(accx[mi][ni][r] - mx[mi][r]);
                bb += __expf(accy[mi][ni][r] - my_[mi][r]);
            }
            sx[mi][r] = a; sy[mi][r] = bb;
        }
#pragma unroll
    for (int off = 1; off < 16; off <<= 1)
#pragma unroll
        for (int mi = 0; mi < 2; ++mi)
#pragma unroll
            for (int r = 0; r < 4; ++r) {
                sx[mi][r] += __shfl_xor(sx[mi][r], off);
                sy[mi][r] += __shfl_xor(sy[mi][r], off);
            }
    if (lm == 0)
#pragma unroll
        for (int mi = 0; mi < 2; ++mi)
#pragma unroll
            for (int r = 0; r < 4; ++r) {
                Ssx[wave][mi * 16 + lq * 4 + r] = sx[mi][r];
                Ssy[wave][mi * 16 + lq * 4 + r] = sy[mi][r];
            }
    __syncthreads();
    float shx[2][4], invy[2][4];
#pragma unroll
    for (int mi = 0; mi < 2; ++mi)
#pragma unroll
        for (int r = 0; r < 4; ++r) {
            const int row = mi * 16 + lq * 4 + r;
            const float ssx = Ssx[0][row] + Ssx[1][row] + Ssx[2][row] + Ssx[3][row];
            const float ssy = Ssy[0][row] + Ssy[1][row] + Ssy[2][row] + Ssy[3][row];
            shx[mi][r]  = mx[mi][r] + __logf(ssx);   // logp shift
            invy[mi][r] = 1.f / ssy;                 // q scale
        }

    // ---- T partial + per-element logp/q stores (valid rows m < 28 only)
    float T = 0.f;
#pragma unroll
    for (int mi = 0; mi < 2; ++mi)
#pragma unroll
        for (int r = 0; r < 4; ++r) {
            const int m = mi * 16 + lq * 4 + r;
            if (m < 28) {
                const int img = (m >= 14) ? 1 : 0;
                const int pj  = m - img * 14;
                const size_t lb = ((size_t)(pi * 64 + ig * 2 + img) * 14 + pj) * 384
                                  + wave * 96 + lm;
                const float sh  = shx[mi][r];
                const float mm  = my_[mi][r];
                const float inv = invy[mi][r];
#pragma unroll
                for (int ni = 0; ni < 6; ++ni) {
                    const float lp = accx[mi][ni][r] - sh;
                    const float qv = __expf(accy[mi][ni][r] - mm) * inv;
                    T += lp * qv;
                    Lg[lb + ni * 16] = lp;
                    Qg[lb + ni * 16] = qv;
                }
            }
        }
#pragma unroll
    for (int off = 32; off > 0; off >>= 1) T += __shfl_xor(T, off);
    if (lane == 0) sT[wave] = T;
    __syncthreads();
    if (tid == 0) atomicAdd(&scal[0], sT[0] + sT[1] + sT[2] + sT[3]);
}

// ---------------- fin: per-position L/Q col sums -> S; final scalar ---------
// grid 196 (one block per position p = pi*14+pj), block 384 = 6 waves.
__global__ __launch_bounds__(384) void fin(const float* __restrict__ Lg,
                                           const float* __restrict__ Qg,
                                           float* __restrict__ scal,
                                           float* __restrict__ out) {
    const int p  = blockIdx.x;
    const int pi = p / 14;
    const int pj = p - pi * 14;
    const int c  = threadIdx.x;                // 0..383
    float L = 0.f, Q = 0.f;
#pragma unroll 4
    for (int img = 0; img < 64; ++img) {
        const size_t o = ((size_t)(pi * 64 + img) * 14 + pj) * 384 + c;
        L += Lg[o];
        Q += Qg[o];
    }
    float s = L * Q;
#pragma unroll
    for (int off = 32; off > 0; off >>= 1) s += __shfl_xor(s, off);
    __shared__ float sw[6];
    if ((c & 63) == 0) sw[c >> 6] = s;
    __syncthreads();
    if (c == 0) {
        const float Sp = sw[0] + sw[1] + sw[2] + sw[3] + sw[4] + sw[5];
        atomicAdd(&scal[1], Sp);
        __threadfence();
        const int old = atomicAdd((int*)&scal[3], 1);
        if (old == POS - 1) {
            const float T = atomicAdd(&scal[0], 0.f);   // coherent read-back
            const float S = atomicAdd(&scal[1], 0.f);
            out[0] = 63.f * T / (S - T);
        }
    }
}

extern "C" void kernel_launch(void* const* d_in, const int* in_sizes, int n_in,
                              void* d_out, int out_size, void* d_ws, size_t ws_size,
                              hipStream_t stream) {
    const float* x = (const float*)d_in[0];   // (64,3,224,224)
    const float* y = (const float*)d_in[1];   // (64,3,224,224)
    const float* W = (const float*)d_in[2];   // (384,768)
    const float* b = (const float*)d_in[3];   // (384,)
    float* out = (float*)d_out;

    char* ws = (char*)d_ws;
    float*    scal  = (float*)ws;                      // 64 B (pad to 1 KB)
    ushort_t* Wfrag = (ushort_t*)(ws + 1024);          // 589,824 B
    float*    Lg    = (float*)(ws + 590848);           // 19,267,584 B
    float*    Qg    = (float*)(ws + 19858432);         // 19,267,584 B

    prep<<<144, 256, 0, stream>>>(W, Wfrag, scal);
    pef<<<448, 256, 0, stream>>>(x, y, Wfrag, b, scal, Lg, Qg);
    fin<<<196, 384, 0, stream>>>(Lg, Qg, scal, out);
}